// Round 5
// baseline (31.518 us; speedup 1.0000x reference)
//
#include <hip/hip_runtime.h>

#define Bq 32
#define Sq 8
#define Lq 128
#define Dq 768
#define Aq 10
#define Tq 8

constexpr int D4   = Dq / 4;     // 192 float4 columns
constexpr int NBS  = Bq * Sq;    // 256
constexpr int NBSA = NBS * Aq;   // 2560

// One block per (b,s), 15 waves:
//   waves 0-11 : mean-pool stream, 4 row-groups x 3 col-waves (32 rows x 64
//                float4 columns each), partial sums -> LDS, combine after B2.
//   waves 12-14: arg sets pred/arg0/arg1 (ballot-based, no LDS).
// Every wave executes exactly two __syncthreads (wave-uniform branch).
__global__ __launch_bounds__(960) void srl_fused_k(
    const int* __restrict__ sids, const float* __restrict__ mask,
    const float* __restrict__ emb, const int* __restrict__ pred,
    const int* __restrict__ a0, const int* __restrict__ a1,
    float* __restrict__ out)
{
    int bs   = blockIdx.x;          // 0..255
    int tid  = threadIdx.x;
    int wv   = tid >> 6;            // 0..14
    int lane = tid & 63;

    __shared__ float  marr[Lq];
    __shared__ float4 red[4][D4];

    if (wv < 12) {
        // ---------------- mean pool ---------------------------------------
        if (tid < Lq) marr[tid] = mask[(size_t)bs * Lq + tid];

        // per-wave mask count (cheap, redundant; only waves 0-2 use inv)
        float mv = mask[(size_t)bs * Lq + lane] +
                   mask[(size_t)bs * Lq + 64 + lane];
        for (int off = 32; off > 0; off >>= 1)
            mv += __shfl_xor(mv, off);
        float inv = 1.0f / fmaxf(mv, 1.0f);      // clip(count, 1, None)

        __syncthreads();                          // B1: marr ready

        int g = tid / 192;                        // row group 0..3
        int c = tid - g * 192;                    // float4 column 0..191

        const float4* eb = (const float4*)emb +
                           (size_t)bs * Lq * D4 + (size_t)(g * 32) * D4 + c;
        float4 acc = make_float4(0.f, 0.f, 0.f, 0.f);
#pragma unroll 16
        for (int l = 0; l < 32; ++l) {
            float  m = marr[g * 32 + l];          // LDS broadcast
            float4 v = eb[(size_t)l * D4];        // coalesced 16B/lane
            acc.x += v.x * m; acc.y += v.y * m;
            acc.z += v.z * m; acc.w += v.w * m;
        }
        red[g][c] = acc;

        __syncthreads();                          // B2: partials ready

        if (tid < D4) {
            float4 a = red[0][tid], b = red[1][tid];
            float4 cc = red[2][tid], d = red[3][tid];
            float4 r;
            r.x = (a.x + b.x + cc.x + d.x) * inv;
            r.y = (a.y + b.y + cc.y + d.y) * inv;
            r.z = (a.z + b.z + cc.z + d.z) * inv;
            r.w = (a.w + b.w + cc.w + d.w) * inv;
            ((float4*)out)[(size_t)bs * D4 + tid] = r;
        }
        return;
    }

    // ---------------- arg embeddings: wave = set (0:pred 1:arg0 2:arg1) ---
    __syncthreads();                              // B1 (match pool waves)

    int set = wv - 12;
    const int* ids = (set == 0) ? pred : ((set == 1) ? a0 : a1);

    // whole sentence in 2 regs/lane
    int s0 = sids[(size_t)bs * Lq + lane];
    int s1 = sids[(size_t)bs * Lq + 64 + lane];

    const float4* eb = (const float4*)emb + (size_t)bs * Lq * D4;

    for (int a = 0; a < Aq; ++a) {
        int bsa = bs * Aq + a;
        int idv = (lane < Tq) ? ids[(size_t)bsa * Tq + lane] : 0;

        // last t (descending) whose nonzero id occurs in the sentence
        unsigned long long B0 = 0, B1 = 0;
        int ccount = 0;
#pragma unroll
        for (int t = Tq - 1; t >= 0; --t) {
            if (ccount == 0) {                       // wave-uniform
                int idt = __shfl(idv, t);
                if (idt != 0) {
                    unsigned long long b0 = __ballot(s0 == idt);
                    unsigned long long b1 = __ballot(s1 == idt);
                    int c = (int)(__popcll(b0) + __popcll(b1));
                    if (c > 0) { B0 = b0; B1 = b1; ccount = c; }
                }
            }
        }

        // gather matched rows (uniform bit loops, ascending l: deterministic)
        float4 acc0 = make_float4(0.f, 0.f, 0.f, 0.f);
        float4 acc1 = acc0, acc2 = acc0;
        unsigned long long b = B0;
        while (b) {
            int l = (int)__builtin_ctzll(b); b &= b - 1;
            float4 v0 = eb[(size_t)l * D4 + lane];
            float4 v1 = eb[(size_t)l * D4 + 64 + lane];
            float4 v2 = eb[(size_t)l * D4 + 128 + lane];
            acc0.x += v0.x; acc0.y += v0.y; acc0.z += v0.z; acc0.w += v0.w;
            acc1.x += v1.x; acc1.y += v1.y; acc1.z += v1.z; acc1.w += v1.w;
            acc2.x += v2.x; acc2.y += v2.y; acc2.z += v2.z; acc2.w += v2.w;
        }
        b = B1;
        while (b) {
            int l = (int)__builtin_ctzll(b) + 64; b &= b - 1;
            float4 v0 = eb[(size_t)l * D4 + lane];
            float4 v1 = eb[(size_t)l * D4 + 64 + lane];
            float4 v2 = eb[(size_t)l * D4 + 128 + lane];
            acc0.x += v0.x; acc0.y += v0.y; acc0.z += v0.z; acc0.w += v0.w;
            acc1.x += v1.x; acc1.y += v1.y; acc1.z += v1.z; acc1.w += v1.w;
            acc2.x += v2.x; acc2.y += v2.y; acc2.z += v2.z; acc2.w += v2.w;
        }

        float inv = (ccount > 0) ? 1.0f / (float)ccount : 0.0f;
        float4* o4 = (float4*)out +
                     ((size_t)NBS + (size_t)set * NBSA + bsa) * D4;
        o4[lane]       = make_float4(acc0.x*inv, acc0.y*inv, acc0.z*inv, acc0.w*inv);
        o4[64 + lane]  = make_float4(acc1.x*inv, acc1.y*inv, acc1.z*inv, acc1.w*inv);
        o4[128 + lane] = make_float4(acc2.x*inv, acc2.y*inv, acc2.z*inv, acc2.w*inv);
    }

    __syncthreads();                              // B2 (match pool waves)
}

extern "C" void kernel_launch(void* const* d_in, const int* in_sizes, int n_in,
                              void* d_out, int out_size, void* d_ws, size_t ws_size,
                              hipStream_t stream) {
    const int*   sids = (const int*)d_in[0];
    const float* mask = (const float*)d_in[1];
    const float* emb  = (const float*)d_in[2];
    const int*   pred = (const int*)d_in[3];
    const int*   a0   = (const int*)d_in[4];
    const int*   a1   = (const int*)d_in[5];
    float* out = (float*)d_out;

    srl_fused_k<<<NBS, 960, 0, stream>>>(sids, mask, emb, pred, a0, a1, out);
}

// Round 6
// 28.057 us; speedup vs baseline: 1.1234x; 1.1234x over previous
//
#include <hip/hip_runtime.h>

#define Bq 32
#define Sq 8
#define Lq 128
#define Dq 768
#define Aq 10
#define Tq 8

typedef float f32x4 __attribute__((ext_vector_type(4)));

constexpr int D4    = Dq / 4;       // 192 float4 columns
constexpr int NBS   = Bq * Sq;      // 256
constexpr int NBSA  = NBS * Aq;     // 2560
constexpr int NPOOL = NBS;          // 256 pool blocks (one per b,s)
constexpr int NARG  = NBS;          // 256 arg blocks (one per b,s; wave=set)

__global__ __launch_bounds__(192) void srl_fused_k(
    const int* __restrict__ sids, const float* __restrict__ mask,
    const float* __restrict__ emb, const int* __restrict__ pred,
    const int* __restrict__ a0, const int* __restrict__ a1,
    float* __restrict__ out)
{
    int bid = blockIdx.x;
    int tid = threadIdx.x;

    if (bid < NPOOL) {
        // ---- mean pool: block = (b,s); thread = float4 column; 128 rows --
        // Non-temporal loads: stream-once data, don't churn the 4MB XCD L2.
        int bs = bid;
        __shared__ float marr[Lq];
        __shared__ float msum;

        if (tid < Lq) marr[tid] = mask[(size_t)bs * Lq + tid];
        if (tid < 64) {
            float mv = mask[(size_t)bs * Lq + tid] +
                       mask[(size_t)bs * Lq + 64 + tid];
            for (int off = 32; off > 0; off >>= 1)
                mv += __shfl_xor(mv, off);
            if (tid == 0) msum = mv;
        }
        __syncthreads();

        const f32x4* eb = (const f32x4*)emb + (size_t)bs * Lq * D4 + tid;
        f32x4 acc = {0.f, 0.f, 0.f, 0.f};
#pragma unroll 16
        for (int l = 0; l < Lq; ++l) {
            float m  = marr[l];                              // LDS broadcast
            f32x4 v  = __builtin_nontemporal_load(&eb[(size_t)l * D4]);
            acc += v * m;
        }
        float inv = 1.0f / fmaxf(msum, 1.0f);   // clip(count,1,None)
        f32x4 r = acc * inv;
        __builtin_nontemporal_store(r, (f32x4*)out + (size_t)bs * D4 + tid);
        return;
    }

    // ---- arg embeddings: block = (b,s); wave = set; loop a = 0..9 --------
    int bs   = bid - NPOOL;
    int set  = tid >> 6;               // wave index = set (0:pred 1:a0 2:a1)
    int lane = tid & 63;
    const int* ids = (set == 0) ? pred : ((set == 1) ? a0 : a1);

    // whole sentence in 2 regs/lane; no LDS, no barriers
    int s0 = sids[(size_t)bs * Lq + lane];
    int s1 = sids[(size_t)bs * Lq + 64 + lane];

    const f32x4* eb = (const f32x4*)emb + (size_t)bs * Lq * D4;

    for (int a = 0; a < Aq; ++a) {
        int bsa = bs * Aq + a;
        int idv = (lane < Tq) ? ids[(size_t)bsa * Tq + lane] : 0;

        // last t (descending) whose nonzero id occurs in the sentence
        unsigned long long B0 = 0, B1 = 0;
        int ccount = 0;
#pragma unroll
        for (int t = Tq - 1; t >= 0; --t) {
            if (ccount == 0) {                       // wave-uniform
                int idt = __shfl(idv, t);
                if (idt != 0) {
                    unsigned long long b0 = __ballot(s0 == idt);
                    unsigned long long b1 = __ballot(s1 == idt);
                    int c = (int)(__popcll(b0) + __popcll(b1));
                    if (c > 0) { B0 = b0; B1 = b1; ccount = c; }
                }
            }
        }

        // gather matched rows (uniform bit loops, ascending l: deterministic)
        // normal loads: these re-read what pool streamed; L3 serves them.
        f32x4 acc0 = {0.f, 0.f, 0.f, 0.f};
        f32x4 acc1 = acc0, acc2 = acc0;
        unsigned long long b = B0;
        while (b) {
            int l = (int)__builtin_ctzll(b); b &= b - 1;
            acc0 += eb[(size_t)l * D4 + lane];
            acc1 += eb[(size_t)l * D4 + 64 + lane];
            acc2 += eb[(size_t)l * D4 + 128 + lane];
        }
        b = B1;
        while (b) {
            int l = (int)__builtin_ctzll(b) + 64; b &= b - 1;
            acc0 += eb[(size_t)l * D4 + lane];
            acc1 += eb[(size_t)l * D4 + 64 + lane];
            acc2 += eb[(size_t)l * D4 + 128 + lane];
        }

        float inv = (ccount > 0) ? 1.0f / (float)ccount : 0.0f;
        f32x4* o4 = (f32x4*)out +
                    ((size_t)NBS + (size_t)set * NBSA + bsa) * D4;
        __builtin_nontemporal_store(acc0 * inv, o4 + lane);
        __builtin_nontemporal_store(acc1 * inv, o4 + 64 + lane);
        __builtin_nontemporal_store(acc2 * inv, o4 + 128 + lane);
    }
}

extern "C" void kernel_launch(void* const* d_in, const int* in_sizes, int n_in,
                              void* d_out, int out_size, void* d_ws, size_t ws_size,
                              hipStream_t stream) {
    const int*   sids = (const int*)d_in[0];
    const float* mask = (const float*)d_in[1];
    const float* emb  = (const float*)d_in[2];
    const int*   pred = (const int*)d_in[3];
    const int*   a0   = (const int*)d_in[4];
    const int*   a1   = (const int*)d_in[5];
    float* out = (float*)d_out;

    srl_fused_k<<<NPOOL + NARG, 192, 0, stream>>>(sids, mask, emb,
                                                  pred, a0, a1, out);
}

// Round 7
// 26.779 us; speedup vs baseline: 1.1770x; 1.0477x over previous
//
#include <hip/hip_runtime.h>

#define Bq 32
#define Sq 8
#define Lq 128
#define Dq 768
#define Aq 10
#define Tq 8

typedef float f32x4 __attribute__((ext_vector_type(4)));

constexpr int D4    = Dq / 4;       // 192 float4 columns
constexpr int NBS   = Bq * Sq;      // 256
constexpr int NBSA  = NBS * Aq;     // 2560
constexpr int NPOOL = NBS * 3;      // 768 pool blocks: (bs, D-third), 1 wave
constexpr int NARG  = NBS * 3;      // 768 arg blocks: (bs, set), 1 wave

// All blocks are a single 64-lane wave. Pool blocks stream 131KB each
// (128 rows x 64 float4 cols); arg blocks do the ballot-select + gather.
// Fine granularity -> per-CU load is ~3 pool + 3 arg waves regardless of
// dispatch order; no multi-block combine needed (full L-reduction per block).
__global__ __launch_bounds__(64) void srl_fused_k(
    const int* __restrict__ sids, const float* __restrict__ mask,
    const float* __restrict__ emb, const int* __restrict__ pred,
    const int* __restrict__ a0, const int* __restrict__ a1,
    float* __restrict__ out)
{
    int bid  = blockIdx.x;
    int lane = threadIdx.x;          // 0..63

    if (bid < NPOOL) {
        // ---- mean pool: block = (bs, third); wave owns 64 float4 columns -
        int bs    = bid / 3;
        int third = bid - bs * 3;

        __shared__ float marr[Lq];
        float m0 = mask[(size_t)bs * Lq + lane];
        float m1 = mask[(size_t)bs * Lq + 64 + lane];
        marr[lane]      = m0;
        marr[64 + lane] = m1;
        float mv = m0 + m1;                       // wave butterfly count
        for (int off = 32; off > 0; off >>= 1)
            mv += __shfl_xor(mv, off);
        float inv = 1.0f / fmaxf(mv, 1.0f);       // clip(count,1,None)
        __syncthreads();                          // single-wave: just waitcnt

        const f32x4* eb = (const f32x4*)emb +
                          (size_t)bs * Lq * D4 + third * 64 + lane;
        f32x4 acc = {0.f, 0.f, 0.f, 0.f};
#pragma unroll 16
        for (int l = 0; l < Lq; ++l) {
            float m = marr[l];                    // LDS broadcast
            f32x4 v = eb[(size_t)l * D4];         // coalesced 1KB/wave
            acc += v * m;
        }
        f32x4 r = acc * inv;
        ((f32x4*)out)[(size_t)bs * D4 + third * 64 + lane] = r;
        return;
    }

    // ---- arg embeddings: block = (bs, set); one wave --------------------
    int j   = bid - NPOOL;
    int bs  = j / 3;
    int set = j - bs * 3;              // 0:pred 1:arg0 2:arg1
    const int* ids = (set == 0) ? pred : ((set == 1) ? a0 : a1);

    // whole sentence in 2 regs/lane; no LDS, no barriers
    int s0 = sids[(size_t)bs * Lq + lane];
    int s1 = sids[(size_t)bs * Lq + 64 + lane];

    const f32x4* eb = (const f32x4*)emb + (size_t)bs * Lq * D4;

    for (int a = 0; a < Aq; ++a) {
        int bsa = bs * Aq + a;
        int idv = (lane < Tq) ? ids[(size_t)bsa * Tq + lane] : 0;

        // last t (descending) whose nonzero id occurs in the sentence
        unsigned long long B0 = 0, B1 = 0;
        int ccount = 0;
#pragma unroll
        for (int t = Tq - 1; t >= 0; --t) {
            if (ccount == 0) {                       // wave-uniform
                int idt = __shfl(idv, t);
                if (idt != 0) {
                    unsigned long long b0 = __ballot(s0 == idt);
                    unsigned long long b1 = __ballot(s1 == idt);
                    int c = (int)(__popcll(b0) + __popcll(b1));
                    if (c > 0) { B0 = b0; B1 = b1; ccount = c; }
                }
            }
        }

        // gather matched rows (uniform bit loops, ascending l: deterministic)
        f32x4 acc0 = {0.f, 0.f, 0.f, 0.f};
        f32x4 acc1 = acc0, acc2 = acc0;
        unsigned long long b = B0;
        while (b) {
            int l = (int)__builtin_ctzll(b); b &= b - 1;
            acc0 += eb[(size_t)l * D4 + lane];
            acc1 += eb[(size_t)l * D4 + 64 + lane];
            acc2 += eb[(size_t)l * D4 + 128 + lane];
        }
        b = B1;
        while (b) {
            int l = (int)__builtin_ctzll(b) + 64; b &= b - 1;
            acc0 += eb[(size_t)l * D4 + lane];
            acc1 += eb[(size_t)l * D4 + 64 + lane];
            acc2 += eb[(size_t)l * D4 + 128 + lane];
        }

        float inv = (ccount > 0) ? 1.0f / (float)ccount : 0.0f;
        f32x4* o4 = (f32x4*)out +
                    ((size_t)NBS + (size_t)set * NBSA + bsa) * D4;
        o4[lane]       = acc0 * inv;
        o4[64 + lane]  = acc1 * inv;
        o4[128 + lane] = acc2 * inv;
    }
}

extern "C" void kernel_launch(void* const* d_in, const int* in_sizes, int n_in,
                              void* d_out, int out_size, void* d_ws, size_t ws_size,
                              hipStream_t stream) {
    const int*   sids = (const int*)d_in[0];
    const float* mask = (const float*)d_in[1];
    const float* emb  = (const float*)d_in[2];
    const int*   pred = (const int*)d_in[3];
    const int*   a0   = (const int*)d_in[4];
    const int*   a1   = (const int*)d_in[5];
    float* out = (float*)d_out;

    srl_fused_k<<<NPOOL + NARG, 64, 0, stream>>>(sids, mask, emb,
                                                 pred, a0, a1, out);
}